// Round 15
// baseline (194.003 us; speedup 1.0000x reference)
//
#include <hip/hip_runtime.h>

// VQ-VAE vector quantizer, MI355X (gfx950).
// z: [B=32, C=256, H=32, W=32] fp32; emb: [K=1024, C=256] fp32.
// Outputs (flat f32): z_q [B,C,H,W] (8388608) | loss (1) | idx-as-float (32768).
//
// score = ||e||^2 - 2 z.e via ONE bf16 MFMA (A = bf16(-2z), B = bf16(e)),
// LDS-staged B chunks with simple dbuf (R12's 82us version — R13 lesson:
// counted-vmcnt pipeline was not the pacer at 2 blocks/CU and cost 7%).
// Top-2 tracked as packed u64 keys (ord(v)<<32|k); shuffle merge network
// reconstructs per-pixel top-3.
//   gap3 < THR -> list3: full bit-exact numpy-fp32 rescan (~tens of px)
//   gap2 < THR -> list2: np-exact compare of {i1,i2}, ONE WAVE PER ENTRY
//     (R13 lesson: batch-of-32 npfix was 79us of serial latency at 1.5%
//      occupancy; the bit-exact chains are short and independent -> one
//      chain per lane, 24 lanes/entry, combines in numpy's exact order).
// np-winner is within 7e-5 of the exact min; bf16 noise sigma ~2.6e-5;
// THR=2.5e-4 margins proven across R3-R13 runs.

#define BB     32
#define CDIM   256
#define HW     1024
#define KK     1024
#define NPIX   (BB * HW)

#define THR     2.5e-4f
#define LISTCAP 16384
#define FPX     8

typedef __attribute__((ext_vector_type(8))) short bf16x8;
typedef __attribute__((ext_vector_type(4))) float f32x4;
typedef unsigned long long u64;
typedef unsigned int u32;

__device__ __forceinline__ unsigned short bf16_rn(float f) {
    unsigned int u = __float_as_uint(f);
    unsigned int r = u + 0x7fffu + ((u >> 16) & 1u);   // RNE
    return (unsigned short)(r >> 16);
}
__device__ __forceinline__ f32x4 mfma16(bf16x8 a, bf16x8 b, f32x4 c) {
    return __builtin_amdgcn_mfma_f32_16x16x32_bf16(a, b, c, 0, 0, 0);
}
__device__ __forceinline__ u32 ordf(float v) {
    const u32 b = __float_as_uint(v);
    return b ^ ((u32)((int)b >> 31) | 0x80000000u);
}
__device__ __forceinline__ float unordf(u32 u) {
    const u32 b = (u & 0x80000000u) ? (u ^ 0x80000000u) : ~u;
    return __uint_as_float(b);
}
__device__ __forceinline__ u64 min64(u64 a, u64 b) { return a < b ? a : b; }
__device__ __forceinline__ u64 max64(u64 a, u64 b) { return a > b ? a : b; }

// ---------------------------------------------------- numpy pairwise replica
__device__ __forceinline__ float pw128_sq(const float* a) {
#pragma clang fp contract(off)
    float4 u = *(const float4*)(a);
    float4 v = *(const float4*)(a + 4);
    float r0 = u.x * u.x, r1 = u.y * u.y, r2 = u.z * u.z, r3 = u.w * u.w;
    float r4 = v.x * v.x, r5 = v.y * v.y, r6 = v.z * v.z, r7 = v.w * v.w;
    for (int i = 8; i < 128; i += 8) {
        float4 p = *(const float4*)(a + i);
        float4 q = *(const float4*)(a + i + 4);
        float s0 = p.x * p.x; r0 = r0 + s0;
        float s1 = p.y * p.y; r1 = r1 + s1;
        float s2 = p.z * p.z; r2 = r2 + s2;
        float s3 = p.w * p.w; r3 = r3 + s3;
        float s4 = q.x * q.x; r4 = r4 + s4;
        float s5 = q.y * q.y; r5 = r5 + s5;
        float s6 = q.z * q.z; r6 = r6 + s6;
        float s7 = q.w * q.w; r7 = r7 + s7;
    }
    return ((r0 + r1) + (r2 + r3)) + ((r4 + r5) + (r6 + r7));
}

// ---------------- prep: cnt reset + np-exact e-norms + bf16 swizzled emb
// ehi layout (chunk-contiguous fragments):
// off = ((kt*8+ks)*16 + k16)*512 + (lk*16+li)*8 + cj
__global__ __launch_bounds__(256)
void prep_kernel(const float* __restrict__ emb,
                 unsigned short* __restrict__ ehi,
                 float* __restrict__ enorm, int* __restrict__ cnt) {
    const int k = blockIdx.x * 256 + threadIdx.x;   // grid 4 x 256
    if (k == 0) { cnt[0] = 0; cnt[1] = 0; }
    const float* e = emb + (size_t)k * CDIM;
    float s;
    {
#pragma clang fp contract(off)
        float L = pw128_sq(e);
        float R = pw128_sq(e + 128);
        s = L + R;
    }
    enorm[k] = s;
    const int kt = k >> 8, k16 = (k >> 4) & 15, li = k & 15;
#pragma unroll
    for (int c4 = 0; c4 < 64; ++c4) {
        const int c = c4 * 4;
        const float4 v = *(const float4*)(e + c);
        ushort4 hv;
        hv.x = bf16_rn(v.x); hv.y = bf16_rn(v.y);
        hv.z = bf16_rn(v.z); hv.w = bf16_rn(v.w);
        const int ks = c >> 5, lk = (c >> 3) & 3, cj = c & 7;
        const int off = (((kt * 8 + ks) * 16 + k16) << 9) + (lk * 16 + li) * 8 + cj;
        *(ushort4*)(ehi + off) = hv;
    }
}

// ---------------------------------------------------------- MFMA argmin
// R12's proven structure: 64 px x 1024 codes, 4 waves pixel-split,
// B chunks (16 KB) double-buffered via global_load_lds + __syncthreads.
__global__ __launch_bounds__(256, 2)
void argmin_mfma_kernel(const float* __restrict__ z,
                        const unsigned short* __restrict__ ehi,
                        const float* __restrict__ enorm,
                        int* __restrict__ idx_i, float* __restrict__ idx_f,
                        int* __restrict__ cnt, int* __restrict__ list2,
                        int* __restrict__ list3) {
    __shared__ __align__(16) unsigned short zhi[64][272];
    __shared__ __align__(16) unsigned short blds[2][8192];   // 2 x 16 KB

    const int t    = threadIdx.x;
    const int px0  = blockIdx.x * 64;
    const int b    = px0 >> 10;
    const int hw0  = px0 & 1023;
    const int wn   = t >> 6;
    const int lane = t & 63;
    const int li   = lane & 15;
    const int lk   = lane >> 4;

    auto stage = [&](int ch, int buf) {
#pragma unroll
        for (int p = 0; p < 4; ++p) {
            const int part = wn * 4 + p;                    // 1 KB per part
            const unsigned short* gsl = ehi + (size_t)ch * 8192 + part * 512 + lane * 8;
            unsigned short* ldst = &blds[buf][part * 512];
            __builtin_amdgcn_global_load_lds(
                (const __attribute__((address_space(1))) unsigned int*)(const void*)gsl,
                (__attribute__((address_space(3))) unsigned int*)(void*)ldst,
                16, 0, 0);
        }
    };

#pragma unroll
    for (int it = 0; it < 16; ++it) {
        const int c     = it * 16 + (t >> 4);
        const int chunk = t & 15;
        const f32x4 v = __builtin_nontemporal_load(
            (const f32x4*)(z + ((size_t)(b * 256 + c)) * 1024 + hw0 + chunk * 4));
#pragma unroll
        for (int i = 0; i < 4; ++i) {
            const int ie = (i + chunk) & 3;
            const int px = chunk * 4 + ie;
            zhi[px][c] = bf16_rn(-2.0f * v[ie]);
        }
    }
    stage(0, 0);
    __syncthreads();

    u64 K1[4], K2[4];
#pragma unroll
    for (int r = 0; r < 4; ++r) { K1[r] = ~0ull; K2[r] = ~0ull; }

    f32x4 acc[16];

    for (int ch = 0; ch < 32; ++ch) {        // chunk = kt*8 + ks
        const int kt = ch >> 3;
        const int ks = ch & 7;
        const int buf = ch & 1;

        if (ks == 0) {
#pragma unroll
            for (int ni = 0; ni < 16; ++ni) {
                const float en = enorm[kt * 256 + ni * 16 + li];
                acc[ni][0] = en; acc[ni][1] = en; acc[ni][2] = en; acc[ni][3] = en;
            }
        }

        if (ch < 31) stage(ch + 1, buf ^ 1);

        const bf16x8 A = *(const bf16x8*)&zhi[wn * 16 + li][lk * 8 + ks * 32];
#pragma unroll
        for (int ni = 0; ni < 16; ++ni) {
            const bf16x8 Bf = *(const bf16x8*)&blds[buf][ni * 512 + lane * 8];
            acc[ni] = mfma16(A, Bf, acc[ni]);
        }

        if (ks == 7) {
#pragma unroll
            for (int ni = 0; ni < 16; ++ni) {
                const u32 k = (u32)(kt * 256 + ni * 16 + li);
#pragma unroll
                for (int r = 0; r < 4; ++r) {
                    const u64 key = ((u64)ordf(acc[ni][r]) << 32) | k;
                    const u64 mx  = max64(K1[r], key);
                    K1[r] = min64(K1[r], key);
                    K2[r] = min64(K2[r], mx);
                }
            }
        }
        __syncthreads();
    }

    // cross-lane merge over the 16 li lanes: 3-list merge network
    u64 K3[4];
#pragma unroll
    for (int r = 0; r < 4; ++r) K3[r] = ~0ull;
#pragma unroll
    for (int m = 1; m < 16; m <<= 1) {
#pragma unroll
        for (int r = 0; r < 4; ++r) {
            const u64 b1 = __shfl_xor(K1[r], m, 64);
            const u64 b2 = __shfl_xor(K2[r], m, 64);
            const u64 b3 = __shfl_xor(K3[r], m, 64);
            const u64 m1 = min64(K1[r], b1), M1 = max64(K1[r], b1);
            const u64 m2 = min64(K2[r], b2), M2 = max64(K2[r], b2);
            K1[r] = m1;
            K2[r] = min64(M1, m2);
            K3[r] = min64(max64(M1, m2), min64(M2, min64(K3[r], b3)));
        }
    }
    if (li == 0) {
#pragma unroll
        for (int r = 0; r < 4; ++r) {
            const int n  = px0 + wn * 16 + lk * 4 + r;
            const int i1 = (int)(K1[r] & 0xffffffffu);
            const int i2 = (int)(K2[r] & 0xffffffffu);
            const float v1 = unordf((u32)(K1[r] >> 32));
            const float v2 = unordf((u32)(K2[r] >> 32));
            const float v3 = unordf((u32)(K3[r] >> 32));
            idx_i[n] = i1;
            idx_f[n] = (float)i1;
            if (v3 - v1 < THR) {                  // 3+ candidates: full rescan
                const int slot = atomicAdd(&cnt[1], 1);
                if (slot < LISTCAP) list3[slot] = n;
            } else if (v2 - v1 < THR) {           // exactly 2 candidates
                const int slot = atomicAdd(&cnt[0], 1);
                if (slot < LISTCAP) list2[slot] = n | (i2 << 17);
            }
        }
    }
}

// ------------- npfix2: one WAVE per list2 entry; bit-exact np compare of
// {i1,i2}. Chains (np SSE 4-lane dot, np pairwise 8-acc znorm) are mapped
// one-per-lane; lane 0 combines in numpy's exact tree order.
__global__ __launch_bounds__(256)
void npfix2_kernel(const float* __restrict__ z, const float* __restrict__ emb,
                   const float* __restrict__ enorm_np,
                   const int* __restrict__ cnt, const int* __restrict__ list2,
                   int* __restrict__ idx_i, float* __restrict__ idx_f) {
    const int t = threadIdx.x, wv = t >> 6, lane = t & 63;
    const int nflag = min(cnt[0], LISTCAP);

    for (int idx = blockIdx.x * 4 + wv; idx < nflag; idx += gridDim.x * 4) {
        const int e  = list2[idx];
        const int n  = e & 0x1FFFF;
        const int k2 = e >> 17;
        const int k1 = idx_i[n];
        const float* zb = z + (size_t)(n >> 10) * (CDIM * HW) + (n & 1023);

        float acc = 0.f;
        if (lane < 8) {
            // dot chains: lane = cand*4 + j ; l_j = sum_m e[4m+j]*z[4m+j]
            const int cand = lane >> 2, j = lane & 3;
            const int k = cand ? k2 : k1;
            const float* er = emb + (size_t)k * CDIM + j;
            {
#pragma clang fp contract(off)
#pragma unroll
                for (int m = 0; m < 64; ++m) {
                    const float ev = er[4 * m];
                    const float zv = zb[(size_t)(4 * m + j) * HW];
                    const float p  = ev * zv;
                    acc = acc + p;
                }
            }
        } else if (lane < 24) {
            // znorm chains: j = lane-8; half = j>>3 (L/R); jj = j&7
            const int j = lane - 8;
            const int half = j >> 3, jj = j & 7;
            {
#pragma clang fp contract(off)
#pragma unroll
                for (int m = 0; m < 16; ++m) {
                    const int c = half * 128 + 8 * m + jj;
                    const float a = zb[(size_t)c * HW];
                    const float p = a * a;
                    acc = acc + p;
                }
            }
        }

        // gather chain results to lane 0 and combine in numpy's exact order
        const float d10 = __shfl(acc, 0, 64), d11 = __shfl(acc, 1, 64);
        const float d12 = __shfl(acc, 2, 64), d13 = __shfl(acc, 3, 64);
        const float d20 = __shfl(acc, 4, 64), d21 = __shfl(acc, 5, 64);
        const float d22 = __shfl(acc, 6, 64), d23 = __shfl(acc, 7, 64);
        const float r0 = __shfl(acc,  8, 64), r1 = __shfl(acc,  9, 64);
        const float r2 = __shfl(acc, 10, 64), r3 = __shfl(acc, 11, 64);
        const float r4 = __shfl(acc, 12, 64), r5 = __shfl(acc, 13, 64);
        const float r6 = __shfl(acc, 14, 64), r7 = __shfl(acc, 15, 64);
        const float s0 = __shfl(acc, 16, 64), s1 = __shfl(acc, 17, 64);
        const float s2 = __shfl(acc, 18, 64), s3 = __shfl(acc, 19, 64);
        const float s4 = __shfl(acc, 20, 64), s5 = __shfl(acc, 21, 64);
        const float s6 = __shfl(acc, 22, 64), s7 = __shfl(acc, 23, 64);
        if (lane == 0) {
#pragma clang fp contract(off)
            const float L   = ((r0 + r1) + (r2 + r3)) + ((r4 + r5) + (r6 + r7));
            const float R   = ((s0 + s1) + (s2 + s3)) + ((s4 + s5) + (s6 + s7));
            const float znp = L + R;
            const float dot1 = (d10 + d11) + (d12 + d13);
            const float dot2 = (d20 + d21) + (d22 + d23);
            const float S1 = znp + enorm_np[k1];
            const float S2 = znp + enorm_np[k2];
            const float tw1 = 2.0f * dot1;
            const float tw2 = 2.0f * dot2;
            const float dd1 = S1 - tw1;
            const float dd2 = S2 - tw2;
            const bool take2 = (dd2 < dd1) || (dd2 == dd1 && k2 < k1);
            const int bk = take2 ? k2 : k1;
            idx_i[n] = bk;
            idx_f[n] = (float)bk;
        }
    }
}

// ------------- npfix3: full bit-exact numpy rescan (rare 3+-cand pixels)
__global__ __launch_bounds__(256)
void npfix3_kernel(const float* __restrict__ z, const float* __restrict__ emb,
                   const float* __restrict__ enorm_np,
                   const int* __restrict__ cnt, const int* __restrict__ list3,
                   int* __restrict__ idx_i, float* __restrict__ idx_f) {
    __shared__ __align__(16) float zrow[FPX][CDIM];
    __shared__ float znp[FPX];
    __shared__ int   pxn[FPX];
    __shared__ float redv[256];
    __shared__ int   redk[256];
    const int t = threadIdx.x;
    const int nflag = min(cnt[1], LISTCAP);

    for (int base = blockIdx.x * FPX; base < nflag; base += gridDim.x * FPX) {
        const int npx = min(FPX, nflag - base);
        if (t < FPX) pxn[t] = list3[base + (t < npx ? t : npx - 1)];
        __syncthreads();
#pragma unroll
        for (int px = 0; px < FPX; ++px) {
            const int n = pxn[px];
            zrow[px][t] = z[(size_t)(n >> 10) * (CDIM * HW) + (size_t)t * HW + (n & 1023)];
        }
        __syncthreads();
        if (t < FPX) {
#pragma clang fp contract(off)
            float L = pw128_sq(&zrow[t][0]);
            float R = pw128_sq(&zrow[t][128]);
            znp[t] = L + R;
        }
        __syncthreads();

        float bv[FPX]; int bki[FPX];
#pragma unroll
        for (int px = 0; px < FPX; ++px) { bv[px] = 3.4e38f; bki[px] = 0; }

        for (int kj = 0; kj < 4; ++kj) {
            const int k = t + kj * 256;
            const float* er = emb + (size_t)k * CDIM;
            float l[FPX][4];
#pragma unroll
            for (int px = 0; px < FPX; ++px)
#pragma unroll
                for (int j = 0; j < 4; ++j) l[px][j] = 0.f;
            {
#pragma clang fp contract(off)
                for (int m = 0; m < 64; ++m) {
                    const float4 e4 = *(const float4*)(er + 4 * m);
#pragma unroll
                    for (int px = 0; px < FPX; ++px) {
                        const float4 z4 = *(const float4*)(&zrow[px][4 * m]);
                        float p0 = e4.x * z4.x; l[px][0] = l[px][0] + p0;
                        float p1 = e4.y * z4.y; l[px][1] = l[px][1] + p1;
                        float p2 = e4.z * z4.z; l[px][2] = l[px][2] + p2;
                        float p3 = e4.w * z4.w; l[px][3] = l[px][3] + p3;
                    }
                }
#pragma unroll
                for (int px = 0; px < FPX; ++px) {
                    float dot = (l[px][0] + l[px][1]) + (l[px][2] + l[px][3]);
                    float S   = znp[px] + enorm_np[k];
                    float tw  = 2.0f * dot;
                    float d   = S - tw;
                    if (d < bv[px]) { bv[px] = d; bki[px] = k; }
                }
            }
        }
        for (int px = 0; px < FPX; ++px) {
            __syncthreads();
            redv[t] = bv[px]; redk[t] = bki[px];
            __syncthreads();
            for (int s = 128; s > 0; s >>= 1) {
                if (t < s) {
                    const float v2 = redv[t + s];
                    const int   k2 = redk[t + s];
                    if (v2 < redv[t] || (v2 == redv[t] && k2 < redk[t])) {
                        redv[t] = v2; redk[t] = k2;
                    }
                }
                __syncthreads();
            }
            if (t == 0 && px < npx) {
                const int n = pxn[px];
                idx_i[n] = redk[0];
                idx_f[n] = (float)redk[0];
            }
        }
        __syncthreads();
    }
}

// ---------------------------------------------------------------- z_q + loss
__global__ __launch_bounds__(256)
void zq_loss_kernel(const float* __restrict__ z, const float* __restrict__ emb,
                    const int* __restrict__ idx_i, float* __restrict__ zq,
                    double* __restrict__ lpart) {
    const int blk = blockIdx.x;
    const int b   = blk >> 3;
    const int cch = blk & 7;
    const int t   = threadIdx.x;
    const int hw  = t * 4;
    const int n0  = b * HW + hw;

    const float* e0 = emb + (size_t)idx_i[n0 + 0] * CDIM + cch * 32;
    const float* e1 = emb + (size_t)idx_i[n0 + 1] * CDIM + cch * 32;
    const float* e2 = emb + (size_t)idx_i[n0 + 2] * CDIM + cch * 32;
    const float* e3 = emb + (size_t)idx_i[n0 + 3] * CDIM + cch * 32;

    const size_t base = ((size_t)b * CDIM + cch * 32) * HW + hw;
    const float* zb = z + base;
    float*       ob = zq + base;

    float ls = 0.f;
#pragma unroll
    for (int c4 = 0; c4 < 8; ++c4) {
        const float4 a0 = *(const float4*)(e0 + 4 * c4);
        const float4 a1 = *(const float4*)(e1 + 4 * c4);
        const float4 a2 = *(const float4*)(e2 + 4 * c4);
        const float4 a3 = *(const float4*)(e3 + 4 * c4);
        const float av0[4] = {a0.x, a0.y, a0.z, a0.w};
        const float av1[4] = {a1.x, a1.y, a1.z, a1.w};
        const float av2[4] = {a2.x, a2.y, a2.z, a2.w};
        const float av3[4] = {a3.x, a3.y, a3.z, a3.w};
#pragma unroll
        for (int cj = 0; cj < 4; ++cj) {
            const size_t off = (size_t)(c4 * 4 + cj) * HW;
            const f32x4 zv = __builtin_nontemporal_load((const f32x4*)(zb + off));
            f32x4 o;
            o[0] = av0[cj]; o[1] = av1[cj]; o[2] = av2[cj]; o[3] = av3[cj];
            __builtin_nontemporal_store(o, (f32x4*)(ob + off));
            const float d0 = o[0] - zv[0], d1 = o[1] - zv[1];
            const float d2 = o[2] - zv[2], d3 = o[3] - zv[3];
            ls += d0 * d0 + d1 * d1 + d2 * d2 + d3 * d3;
        }
    }

    __shared__ float red[256];
    red[t] = ls;
    __syncthreads();
    if (t < 128) red[t] += red[t + 128];
    __syncthreads();
    if (t < 64) {
        float s = red[t] + red[t + 64];
#pragma unroll
        for (int off = 32; off > 0; off >>= 1) s += __shfl_down(s, off, 64);
        if (t == 0) lpart[blk] = (double)s;
    }
}

__global__ void loss_fin_kernel(const double* __restrict__ lpart,
                                float* __restrict__ loss_out) {
    const int t = threadIdx.x;
    double s = 0.0;
#pragma unroll
    for (int i = 0; i < 4; ++i) s += lpart[t * 4 + i];
#pragma unroll
    for (int off = 32; off > 0; off >>= 1) s += __shfl_down(s, off, 64);
    if (t == 0)
        loss_out[0] = (float)(0.25 * s / (double)((size_t)BB * CDIM * HW));
}

// ---------------------------------------------------------------- launch
extern "C" void kernel_launch(void* const* d_in, const int* in_sizes, int n_in,
                              void* d_out, int out_size, void* d_ws, size_t ws_size,
                              hipStream_t stream) {
    const float* z   = (const float*)d_in[0];
    const float* emb = (const float*)d_in[1];

    float* out  = (float*)d_out;
    float* zq   = out;
    float* loss = out + (size_t)BB * CDIM * HW;
    float* idxf = loss + 1;

    char* ws = (char*)d_ws;
    int*            idx_i = (int*)(ws);                      // 131072 B
    float*          enorm = (float*)(ws + 131072);           // 4096 B
    double*         lpart = (double*)(ws + 135168);          // 2048 B
    int*            cnt   = (int*)(ws + 137216);             // 256 B
    int*            list2 = (int*)(ws + 137472);             // 65536 B
    int*            list3 = (int*)(ws + 203008);             // 65536 B
    unsigned short* ehi   = (unsigned short*)(ws + 268544);  // 524288 B

    prep_kernel<<<KK / 256, 256, 0, stream>>>(emb, ehi, enorm, cnt);

    argmin_mfma_kernel<<<NPIX / 64, 256, 0, stream>>>(z, ehi, enorm,
                                                      idx_i, idxf, cnt,
                                                      list2, list3);
    npfix2_kernel<<<512, 256, 0, stream>>>(z, emb, enorm, cnt, list2,
                                           idx_i, idxf);
    npfix3_kernel<<<64, 256, 0, stream>>>(z, emb, enorm, cnt, list3,
                                          idx_i, idxf);

    zq_loss_kernel<<<BB * 8, 256, 0, stream>>>(z, emb, idx_i, zq, lpart);
    loss_fin_kernel<<<1, 64, 0, stream>>>(lpart, loss);
}